// Round 4
// baseline (198.751 us; speedup 1.0000x reference)
//
#include <hip/hip_runtime.h>
#include <stdint.h>

// GCMConv on MI355X. Data model (verified rounds 0-3):
//   x      : float32 (1,16384,8,3,3,2)  — complex pair = float2
//   weight : float32 (4,9,33)
//   out    : float32 (1,16384,8,3,3,2)
//
// out[u] = sum_{w16<16} ( N1 @ t[w16] + N2 @ t[w16]^+ ) + N(w=32)
//   Nk = sum_v weight[u,v,wk] * w_full[v],  w_full = [w0..3, w0..3^+, I].
//
// Round-3 restructure: 16 threads per site (u=out-channel, g=w16-quarter).
// Phase 1: one transport per thread. Phase 2: each thread 4 w16 slots +
// its v=g share of the w=32 identity term; reduce over g via __shfl_xor
// (g = lane bits 0-1). 262144 threads = 4096 waves -> 3+ waves/SIMD.

#define SPB 16            // sites per block
#define TPB 256           // 16 threads per site
#define NSITES 16384
#define TS_SITE 292       // 16*18 floats + 4 pad
#define TS_W 18
#define NWGT 1188         // 4*9*33

__device__ __forceinline__ int neigh(int s, int a){
    // dims (8,8,16,16): d3 bits[0:4), d2 bits[4:8), d1 bits[8:11), d0 bits[11:14)
    if (a == 3) return (s & ~15)        | ((s + 1)    & 15);
    if (a == 2) return (s & ~(15 << 4)) | ((s + 16)   & (15 << 4));
    if (a == 1) return (s & ~(7 << 8))  | ((s + 256)  & (7 << 8));
    return              (s & ~(7 << 11))| ((s + 2048) & (7 << 11));
}

__global__ __launch_bounds__(TPB, 3)
void gcm_fused(const float* __restrict__ xp,
               const float* __restrict__ wgt,
               float* __restrict__ outp)
{
    __shared__ float lt[SPB * TS_SITE];
    __shared__ float wsm[NWGT];
    const float2* x2 = (const float2*)xp;
    float2* o2 = (float2*)outp;

    const int tid = threadIdx.x;
    const int g   = tid & 3;            // lane bits 0-1 -> shfl_xor reduction
    const int u   = (tid >> 2) & 3;     // output channel / phase1 axis
    const int sl  = tid >> 4;           // site within block
    const int s   = blockIdx.x * SPB + sl;

    // stage weights to LDS
    for (int idx = tid; idx < NWGT; idx += TPB) wsm[idx] = wgt[idx];

    // ============ phase 1: one transport per thread: t[a*4+i] = U_a W_i(s+a^) U_a^+
    {
        const int a = u, i = g;
        float ure[9], uim[9];
        const float2* up = x2 + (s * 8 + a) * 9;
        #pragma unroll
        for (int e = 0; e < 9; e++){ float2 d = up[e]; ure[e] = d.x; uim[e] = d.y; }
        const int sn = neigh(s, a);
        float wre[9], wim[9];
        const float2* wp = x2 + (sn * 8 + 4 + i) * 9;
        #pragma unroll
        for (int e = 0; e < 9; e++){ float2 d = wp[e]; wre[e] = d.x; wim[e] = d.y; }

        float t1re[9], t1im[9];
        #pragma unroll
        for (int r = 0; r < 3; r++){
            #pragma unroll
            for (int k = 0; k < 3; k++){
                float ar = 0.f, ai = 0.f;
                #pragma unroll
                for (int j = 0; j < 3; j++){
                    float a_r = ure[r*3+j], a_i = uim[r*3+j];
                    float b_r = wre[j*3+k], b_i = wim[j*3+k];
                    ar = fmaf(a_r, b_r, ar); ar = fmaf(-a_i, b_i, ar);
                    ai = fmaf(a_r, b_i, ai); ai = fmaf(a_i, b_r, ai);
                }
                t1re[r*3+k] = ar; t1im[r*3+k] = ai;
            }
        }
        // T = T1 * U^+
        float* dst = &lt[sl * TS_SITE + (a * 4 + i) * TS_W];
        #pragma unroll
        for (int r = 0; r < 3; r++){
            #pragma unroll
            for (int k = 0; k < 3; k++){
                float ar = 0.f, ai = 0.f;
                #pragma unroll
                for (int j = 0; j < 3; j++){
                    float a_r = t1re[r*3+j], a_i = t1im[r*3+j];
                    float b_r = ure[k*3+j], b_i = uim[k*3+j];
                    ar = fmaf(a_r, b_r, ar); ar = fmaf(a_i, b_i, ar);
                    ai = fmaf(a_i, b_r, ai); ai = fmaf(-a_r, b_i, ai);
                }
                dst[(r*3+k)*2]     = ar;
                dst[(r*3+k)*2 + 1] = ai;
            }
        }
    }
    __syncthreads();

    // ============ phase 2 ============
    // pass-through copy of u channels (one quarter of lanes)
    if (g == 1){
        const float2* src = x2 + (s * 8 + u) * 9;
        float2* dst = o2 + (s * 8 + u) * 9;
        #pragma unroll
        for (int e = 0; e < 9; e++) dst[e] = src[e];
    }

    // own-site w matrices -> registers
    float wr[4][9], wi[4][9];
    #pragma unroll
    for (int v = 0; v < 4; v++){
        const float2* wp = x2 + (s * 8 + 4 + v) * 9;
        #pragma unroll
        for (int e = 0; e < 9; e++){ float2 d = wp[e]; wr[v][e] = d.x; wi[v][e] = d.y; }
    }

    float cre[9], cim[9];
    #pragma unroll
    for (int e = 0; e < 9; e++){ cre[e] = 0.f; cim[e] = 0.f; }

    const float* wu = wsm + u * 297;     // weight[u][v][w], stride 33 per v

    // --- w == 32 identity term: this thread's v=g share (plain + dagger)
    {
        float c1 = wu[g * 33 + 32];
        float c2 = wu[(4 + g) * 33 + 32];
        #pragma unroll
        for (int i = 0; i < 3; i++){
            #pragma unroll
            for (int j = 0; j < 3; j++){
                const int e = i*3+j, eT = j*3+i;
                cre[e] = fmaf(c1, wr[g][e],  cre[e]);
                cre[e] = fmaf(c2, wr[g][eT], cre[e]);
                cim[e] = fmaf(c1, wi[g][e],  cim[e]);
                cim[e] = fmaf(-c2, wi[g][eT], cim[e]);
            }
        }
        if (g == 0){
            float c8 = wu[8 * 33 + 32];
            cre[0] += c8; cre[4] += c8; cre[8] += c8;
        }
    }

    // --- main loop: 4 w16 slots for this thread
    const float* tbase = &lt[sl * TS_SITE];
    #pragma unroll
    for (int k = 0; k < 4; k++){
        const int w16 = g * 4 + k;
        float tre[9], tim[9];
        {
            const float2* tp = (const float2*)(tbase + w16 * TS_W);
            #pragma unroll
            for (int e = 0; e < 9; e++){ float2 d = tp[e]; tre[e] = d.x; tim[e] = d.y; }
        }
        float nre[9], nim[9];

        // N1 = sum_v weight[u,v,w16] * w_full[v];  C += N1 @ T
        {
            float cv[9];
            #pragma unroll
            for (int v = 0; v < 9; v++) cv[v] = wu[v * 33 + w16];
            #pragma unroll
            for (int i = 0; i < 3; i++){
                #pragma unroll
                for (int j = 0; j < 3; j++){
                    const int e = i*3+j, eT = j*3+i;
                    float nr = (i == j) ? cv[8] : 0.f;
                    float ni = 0.f;
                    #pragma unroll
                    for (int v = 0; v < 4; v++){
                        nr = fmaf(cv[v],    wr[v][e],  nr);
                        nr = fmaf(cv[4+v],  wr[v][eT], nr);
                        ni = fmaf(cv[v],    wi[v][e],  ni);
                        ni = fmaf(-cv[4+v], wi[v][eT], ni);
                    }
                    nre[e] = nr; nim[e] = ni;
                }
            }
        }
        #pragma unroll
        for (int i = 0; i < 3; i++){
            #pragma unroll
            for (int kk = 0; kk < 3; kk++){
                float ar = cre[i*3+kk], ai = cim[i*3+kk];
                #pragma unroll
                for (int j = 0; j < 3; j++){
                    float n_r = nre[i*3+j], n_i = nim[i*3+j];
                    float b_r = tre[j*3+kk], b_i = tim[j*3+kk];
                    ar = fmaf(n_r, b_r, ar); ar = fmaf(-n_i, b_i, ar);
                    ai = fmaf(n_r, b_i, ai); ai = fmaf(n_i, b_r, ai);
                }
                cre[i*3+kk] = ar; cim[i*3+kk] = ai;
            }
        }

        // N2 = sum_v weight[u,v,16+w16] * w_full[v];  C += N2 @ T^+
        {
            float cv[9];
            #pragma unroll
            for (int v = 0; v < 9; v++) cv[v] = wu[v * 33 + 16 + w16];
            #pragma unroll
            for (int i = 0; i < 3; i++){
                #pragma unroll
                for (int j = 0; j < 3; j++){
                    const int e = i*3+j, eT = j*3+i;
                    float nr = (i == j) ? cv[8] : 0.f;
                    float ni = 0.f;
                    #pragma unroll
                    for (int v = 0; v < 4; v++){
                        nr = fmaf(cv[v],    wr[v][e],  nr);
                        nr = fmaf(cv[4+v],  wr[v][eT], nr);
                        ni = fmaf(cv[v],    wi[v][e],  ni);
                        ni = fmaf(-cv[4+v], wi[v][eT], ni);
                    }
                    nre[e] = nr; nim[e] = ni;
                }
            }
        }
        #pragma unroll
        for (int i = 0; i < 3; i++){
            #pragma unroll
            for (int kk = 0; kk < 3; kk++){
                float ar = cre[i*3+kk], ai = cim[i*3+kk];
                #pragma unroll
                for (int j = 0; j < 3; j++){
                    float n_r = nre[i*3+j], n_i = nim[i*3+j];
                    // T^+[j,kk] = ( tre[kk*3+j], -tim[kk*3+j] )
                    float b_r = tre[kk*3+j], b_i = tim[kk*3+j];
                    ar = fmaf(n_r, b_r, ar); ar = fmaf(n_i, b_i, ar);
                    ai = fmaf(-n_r, b_i, ai); ai = fmaf(n_i, b_r, ai);
                }
                cre[i*3+kk] = ar; cim[i*3+kk] = ai;
            }
        }
    }

    // --- reduce partials over g (lane bits 0-1) and store
    #pragma unroll
    for (int e = 0; e < 9; e++){
        cre[e] += __shfl_xor(cre[e], 1);
        cre[e] += __shfl_xor(cre[e], 2);
        cim[e] += __shfl_xor(cim[e], 1);
        cim[e] += __shfl_xor(cim[e], 2);
    }
    if (g == 0){
        float2* dst = o2 + (s * 8 + 4 + u) * 9;
        #pragma unroll
        for (int e = 0; e < 9; e++){ float2 d; d.x = cre[e]; d.y = cim[e]; dst[e] = d; }
    }
}

extern "C" void kernel_launch(void* const* d_in, const int* in_sizes, int n_in,
                              void* d_out, int out_size, void* d_ws, size_t ws_size,
                              hipStream_t stream)
{
    const float* x = (const float*)d_in[0];
    const float* w = (const float*)d_in[1];
    float* out = (float*)d_out;
    dim3 grid(NSITES / SPB);
    dim3 block(TPB);
    hipLaunchKernelGGL(gcm_fused, grid, block, 0, stream, x, w, out);
}

// Round 5
// 163.584 us; speedup vs baseline: 1.2150x; 1.2150x over previous
//
#include <hip/hip_runtime.h>
#include <stdint.h>

// GCMConv on MI355X. Data model (verified rounds 0-3):
//   x      : float32 (1,16384,8,3,3,2)  — complex pair = float2
//   weight : float32 (4,9,33)
//   out    : float32 (1,16384,8,3,3,2)
//
// out[u] = sum_{w16<16} ( N1 @ t[w16] + N2 @ t[w16]^+ ) + N(w=32)
//   Nk = sum_v weight[u,v,wk] * w_full[v],  w_full = [w0..3, w0..3^+, I].
//
// 16 threads per site (u=out-channel, g=w16-quarter). Phase 1: one transport
// per thread. Phase 2: 4 w16 slots per thread; reduce over g via __shfl_xor.
// Round-5 fix: NO dynamically-indexed private arrays (round 4's wr[g][..]
// forced wr/wi to scratch -> 480 MB spill traffic, 145 us). Identity term now
// uses a statically-unrolled v loop with predicated coefficients.

#define SPB 16            // sites per block
#define TPB 256           // 16 threads per site
#define NSITES 16384
#define TS_SITE 292       // 16*18 floats + 4 pad
#define TS_W 18
#define NWGT 1188         // 4*9*33

__device__ __forceinline__ int neigh(int s, int a){
    // dims (8,8,16,16): d3 bits[0:4), d2 bits[4:8), d1 bits[8:11), d0 bits[11:14)
    if (a == 3) return (s & ~15)        | ((s + 1)    & 15);
    if (a == 2) return (s & ~(15 << 4)) | ((s + 16)   & (15 << 4));
    if (a == 1) return (s & ~(7 << 8))  | ((s + 256)  & (7 << 8));
    return              (s & ~(7 << 11))| ((s + 2048) & (7 << 11));
}

__global__ __launch_bounds__(TPB, 3)
void gcm_fused(const float* __restrict__ xp,
               const float* __restrict__ wgt,
               float* __restrict__ outp)
{
    __shared__ float lt[SPB * TS_SITE];
    __shared__ float wsm[NWGT];
    const float2* x2 = (const float2*)xp;
    float2* o2 = (float2*)outp;

    const int tid = threadIdx.x;
    const int g   = tid & 3;            // lane bits 0-1 -> shfl_xor reduction
    const int u   = (tid >> 2) & 3;     // output channel / phase1 axis
    const int sl  = tid >> 4;           // site within block
    const int s   = blockIdx.x * SPB + sl;

    // stage weights to LDS
    for (int idx = tid; idx < NWGT; idx += TPB) wsm[idx] = wgt[idx];

    // ============ phase 1: one transport per thread: t[a*4+i] = U_a W_i(s+a^) U_a^+
    {
        const int a = u, i = g;
        float ure[9], uim[9];
        const float2* up = x2 + (s * 8 + a) * 9;
        #pragma unroll
        for (int e = 0; e < 9; e++){ float2 d = up[e]; ure[e] = d.x; uim[e] = d.y; }
        const int sn = neigh(s, a);
        float wre[9], wim[9];
        const float2* wp = x2 + (sn * 8 + 4 + i) * 9;
        #pragma unroll
        for (int e = 0; e < 9; e++){ float2 d = wp[e]; wre[e] = d.x; wim[e] = d.y; }

        float t1re[9], t1im[9];
        #pragma unroll
        for (int r = 0; r < 3; r++){
            #pragma unroll
            for (int k = 0; k < 3; k++){
                float ar = 0.f, ai = 0.f;
                #pragma unroll
                for (int j = 0; j < 3; j++){
                    float a_r = ure[r*3+j], a_i = uim[r*3+j];
                    float b_r = wre[j*3+k], b_i = wim[j*3+k];
                    ar = fmaf(a_r, b_r, ar); ar = fmaf(-a_i, b_i, ar);
                    ai = fmaf(a_r, b_i, ai); ai = fmaf(a_i, b_r, ai);
                }
                t1re[r*3+k] = ar; t1im[r*3+k] = ai;
            }
        }
        // T = T1 * U^+
        float* dst = &lt[sl * TS_SITE + (a * 4 + i) * TS_W];
        #pragma unroll
        for (int r = 0; r < 3; r++){
            #pragma unroll
            for (int k = 0; k < 3; k++){
                float ar = 0.f, ai = 0.f;
                #pragma unroll
                for (int j = 0; j < 3; j++){
                    float a_r = t1re[r*3+j], a_i = t1im[r*3+j];
                    float b_r = ure[k*3+j], b_i = uim[k*3+j];
                    ar = fmaf(a_r, b_r, ar); ar = fmaf(a_i, b_i, ar);
                    ai = fmaf(a_i, b_r, ai); ai = fmaf(-a_r, b_i, ai);
                }
                dst[(r*3+k)*2]     = ar;
                dst[(r*3+k)*2 + 1] = ai;
            }
        }
    }
    __syncthreads();

    // ============ phase 2 ============
    // pass-through copy of u channels (one quarter of lanes)
    if (g == 1){
        const float2* src = x2 + (s * 8 + u) * 9;
        float2* dst = o2 + (s * 8 + u) * 9;
        #pragma unroll
        for (int e = 0; e < 9; e++) dst[e] = src[e];
    }

    // own-site w matrices -> registers (ALL indices compile-time static)
    float wr[4][9], wi[4][9];
    #pragma unroll
    for (int v = 0; v < 4; v++){
        const float2* wp = x2 + (s * 8 + 4 + v) * 9;
        #pragma unroll
        for (int e = 0; e < 9; e++){ float2 d = wp[e]; wr[v][e] = d.x; wi[v][e] = d.y; }
    }

    float cre[9], cim[9];
    #pragma unroll
    for (int e = 0; e < 9; e++){ cre[e] = 0.f; cim[e] = 0.f; }

    const float* wu = wsm + u * 297;     // weight[u][v][w], stride 33 per v

    // --- w == 32 identity term: thread's v==g share, STATIC unroll + predicated coef
    {
        #pragma unroll
        for (int v = 0; v < 4; v++){
            float c1 = (v == g) ? wu[v * 33 + 32]       : 0.f;
            float c2 = (v == g) ? wu[(4 + v) * 33 + 32] : 0.f;
            #pragma unroll
            for (int i = 0; i < 3; i++){
                #pragma unroll
                for (int j = 0; j < 3; j++){
                    const int e = i*3+j, eT = j*3+i;
                    cre[e] = fmaf(c1, wr[v][e],  cre[e]);
                    cre[e] = fmaf(c2, wr[v][eT], cre[e]);
                    cim[e] = fmaf(c1, wi[v][e],  cim[e]);
                    cim[e] = fmaf(-c2, wi[v][eT], cim[e]);
                }
            }
        }
        if (g == 0){
            float c8 = wu[8 * 33 + 32];
            cre[0] += c8; cre[4] += c8; cre[8] += c8;
        }
    }

    // --- main loop: 4 w16 slots for this thread
    const float* tbase = &lt[sl * TS_SITE];
    #pragma unroll
    for (int k = 0; k < 4; k++){
        const int w16 = g * 4 + k;
        float tre[9], tim[9];
        {
            const float2* tp = (const float2*)(tbase + w16 * TS_W);
            #pragma unroll
            for (int e = 0; e < 9; e++){ float2 d = tp[e]; tre[e] = d.x; tim[e] = d.y; }
        }
        float nre[9], nim[9];

        // N1 = sum_v weight[u,v,w16] * w_full[v];  C += N1 @ T
        {
            float cv[9];
            #pragma unroll
            for (int v = 0; v < 9; v++) cv[v] = wu[v * 33 + w16];
            #pragma unroll
            for (int i = 0; i < 3; i++){
                #pragma unroll
                for (int j = 0; j < 3; j++){
                    const int e = i*3+j, eT = j*3+i;
                    float nr = (i == j) ? cv[8] : 0.f;
                    float ni = 0.f;
                    #pragma unroll
                    for (int v = 0; v < 4; v++){
                        nr = fmaf(cv[v],    wr[v][e],  nr);
                        nr = fmaf(cv[4+v],  wr[v][eT], nr);
                        ni = fmaf(cv[v],    wi[v][e],  ni);
                        ni = fmaf(-cv[4+v], wi[v][eT], ni);
                    }
                    nre[e] = nr; nim[e] = ni;
                }
            }
        }
        #pragma unroll
        for (int i = 0; i < 3; i++){
            #pragma unroll
            for (int kk = 0; kk < 3; kk++){
                float ar = cre[i*3+kk], ai = cim[i*3+kk];
                #pragma unroll
                for (int j = 0; j < 3; j++){
                    float n_r = nre[i*3+j], n_i = nim[i*3+j];
                    float b_r = tre[j*3+kk], b_i = tim[j*3+kk];
                    ar = fmaf(n_r, b_r, ar); ar = fmaf(-n_i, b_i, ar);
                    ai = fmaf(n_r, b_i, ai); ai = fmaf(n_i, b_r, ai);
                }
                cre[i*3+kk] = ar; cim[i*3+kk] = ai;
            }
        }

        // N2 = sum_v weight[u,v,16+w16] * w_full[v];  C += N2 @ T^+
        {
            float cv[9];
            #pragma unroll
            for (int v = 0; v < 9; v++) cv[v] = wu[v * 33 + 16 + w16];
            #pragma unroll
            for (int i = 0; i < 3; i++){
                #pragma unroll
                for (int j = 0; j < 3; j++){
                    const int e = i*3+j, eT = j*3+i;
                    float nr = (i == j) ? cv[8] : 0.f;
                    float ni = 0.f;
                    #pragma unroll
                    for (int v = 0; v < 4; v++){
                        nr = fmaf(cv[v],    wr[v][e],  nr);
                        nr = fmaf(cv[4+v],  wr[v][eT], nr);
                        ni = fmaf(cv[v],    wi[v][e],  ni);
                        ni = fmaf(-cv[4+v], wi[v][eT], ni);
                    }
                    nre[e] = nr; nim[e] = ni;
                }
            }
        }
        #pragma unroll
        for (int i = 0; i < 3; i++){
            #pragma unroll
            for (int kk = 0; kk < 3; kk++){
                float ar = cre[i*3+kk], ai = cim[i*3+kk];
                #pragma unroll
                for (int j = 0; j < 3; j++){
                    float n_r = nre[i*3+j], n_i = nim[i*3+j];
                    // T^+[j,kk] = ( tre[kk*3+j], -tim[kk*3+j] )
                    float b_r = tre[kk*3+j], b_i = tim[kk*3+j];
                    ar = fmaf(n_r, b_r, ar); ar = fmaf(n_i, b_i, ar);
                    ai = fmaf(-n_r, b_i, ai); ai = fmaf(n_i, b_r, ai);
                }
                cre[i*3+kk] = ar; cim[i*3+kk] = ai;
            }
        }
    }

    // --- reduce partials over g (lane bits 0-1) and store
    #pragma unroll
    for (int e = 0; e < 9; e++){
        cre[e] += __shfl_xor(cre[e], 1);
        cre[e] += __shfl_xor(cre[e], 2);
        cim[e] += __shfl_xor(cim[e], 1);
        cim[e] += __shfl_xor(cim[e], 2);
    }
    if (g == 0){
        float2* dst = o2 + (s * 8 + 4 + u) * 9;
        #pragma unroll
        for (int e = 0; e < 9; e++){ float2 d; d.x = cre[e]; d.y = cim[e]; dst[e] = d; }
    }
}

extern "C" void kernel_launch(void* const* d_in, const int* in_sizes, int n_in,
                              void* d_out, int out_size, void* d_ws, size_t ws_size,
                              hipStream_t stream)
{
    const float* x = (const float*)d_in[0];
    const float* w = (const float*)d_in[1];
    float* out = (float*)d_out;
    dim3 grid(NSITES / SPB);
    dim3 block(TPB);
    hipLaunchKernelGGL(gcm_fused, grid, block, 0, stream, x, w, out);
}

// Round 6
// 98.720 us; speedup vs baseline: 2.0133x; 1.6570x over previous
//
#include <hip/hip_runtime.h>
#include <stdint.h>

// GCMConv on MI355X. Data model (verified rounds 0-3):
//   x      : float32 (1,16384,8,3,3,2)  — complex pair = float2
//   weight : float32 (4,9,33)
//   out    : float32 (1,16384,8,3,3,2)
//
// out[u] = sum_{w16<16} ( N1 @ t[w16] + N2 @ t[w16]^+ ) + N(w=32)
//   Nk = sum_v weight[u,v,wk] * w_full[v],  w_full = [w0..3, w0..3^+, I].
//
// 16 threads per site (u=out-channel, g=w16-quarter). Phase 1: one transport
// per thread. Phase 2: 4 w16 slots per thread; reduce over g via __shfl_xor.
// Round-6 fix: __launch_bounds__(256,2). Round 4/5's (256,3) forced a <=128
// VGPR budget (HW wave slots step at 64/128/256) against a ~145-float live
// set -> spill cascade (VGPR=84, ~370 MB scratch traffic). Cap 256 fits it.

#define SPB 16            // sites per block
#define TPB 256           // 16 threads per site
#define NSITES 16384
#define TS_SITE 292       // 16*18 floats + 4 pad
#define TS_W 18
#define NWGT 1188         // 4*9*33

__device__ __forceinline__ int neigh(int s, int a){
    // dims (8,8,16,16): d3 bits[0:4), d2 bits[4:8), d1 bits[8:11), d0 bits[11:14)
    if (a == 3) return (s & ~15)        | ((s + 1)    & 15);
    if (a == 2) return (s & ~(15 << 4)) | ((s + 16)   & (15 << 4));
    if (a == 1) return (s & ~(7 << 8))  | ((s + 256)  & (7 << 8));
    return              (s & ~(7 << 11))| ((s + 2048) & (7 << 11));
}

__global__ __launch_bounds__(TPB, 2)
void gcm_fused(const float* __restrict__ xp,
               const float* __restrict__ wgt,
               float* __restrict__ outp)
{
    __shared__ float lt[SPB * TS_SITE];
    __shared__ float wsm[NWGT];
    const float2* x2 = (const float2*)xp;
    float2* o2 = (float2*)outp;

    const int tid = threadIdx.x;
    const int g   = tid & 3;            // lane bits 0-1 -> shfl_xor reduction
    const int u   = (tid >> 2) & 3;     // output channel / phase1 axis
    const int sl  = tid >> 4;           // site within block
    const int s   = blockIdx.x * SPB + sl;

    // stage weights to LDS
    for (int idx = tid; idx < NWGT; idx += TPB) wsm[idx] = wgt[idx];

    // ============ phase 1: one transport per thread: t[a*4+i] = U_a W_i(s+a^) U_a^+
    {
        const int a = u, i = g;
        float ure[9], uim[9];
        const float2* up = x2 + (s * 8 + a) * 9;
        #pragma unroll
        for (int e = 0; e < 9; e++){ float2 d = up[e]; ure[e] = d.x; uim[e] = d.y; }
        const int sn = neigh(s, a);
        float wre[9], wim[9];
        const float2* wp = x2 + (sn * 8 + 4 + i) * 9;
        #pragma unroll
        for (int e = 0; e < 9; e++){ float2 d = wp[e]; wre[e] = d.x; wim[e] = d.y; }

        float t1re[9], t1im[9];
        #pragma unroll
        for (int r = 0; r < 3; r++){
            #pragma unroll
            for (int k = 0; k < 3; k++){
                float ar = 0.f, ai = 0.f;
                #pragma unroll
                for (int j = 0; j < 3; j++){
                    float a_r = ure[r*3+j], a_i = uim[r*3+j];
                    float b_r = wre[j*3+k], b_i = wim[j*3+k];
                    ar = fmaf(a_r, b_r, ar); ar = fmaf(-a_i, b_i, ar);
                    ai = fmaf(a_r, b_i, ai); ai = fmaf(a_i, b_r, ai);
                }
                t1re[r*3+k] = ar; t1im[r*3+k] = ai;
            }
        }
        // T = T1 * U^+
        float* dst = &lt[sl * TS_SITE + (a * 4 + i) * TS_W];
        #pragma unroll
        for (int r = 0; r < 3; r++){
            #pragma unroll
            for (int k = 0; k < 3; k++){
                float ar = 0.f, ai = 0.f;
                #pragma unroll
                for (int j = 0; j < 3; j++){
                    float a_r = t1re[r*3+j], a_i = t1im[r*3+j];
                    float b_r = ure[k*3+j], b_i = uim[k*3+j];
                    ar = fmaf(a_r, b_r, ar); ar = fmaf(a_i, b_i, ar);
                    ai = fmaf(a_i, b_r, ai); ai = fmaf(-a_r, b_i, ai);
                }
                dst[(r*3+k)*2]     = ar;
                dst[(r*3+k)*2 + 1] = ai;
            }
        }
    }
    __syncthreads();

    // ============ phase 2 ============
    // pass-through copy of u channels (one quarter of lanes)
    if (g == 1){
        const float2* src = x2 + (s * 8 + u) * 9;
        float2* dst = o2 + (s * 8 + u) * 9;
        #pragma unroll
        for (int e = 0; e < 9; e++) dst[e] = src[e];
    }

    // own-site w matrices -> registers (ALL indices compile-time static)
    float wr[4][9], wi[4][9];
    #pragma unroll
    for (int v = 0; v < 4; v++){
        const float2* wp = x2 + (s * 8 + 4 + v) * 9;
        #pragma unroll
        for (int e = 0; e < 9; e++){ float2 d = wp[e]; wr[v][e] = d.x; wi[v][e] = d.y; }
    }

    float cre[9], cim[9];
    #pragma unroll
    for (int e = 0; e < 9; e++){ cre[e] = 0.f; cim[e] = 0.f; }

    const float* wu = wsm + u * 297;     // weight[u][v][w], stride 33 per v

    // --- w == 32 identity term: thread's v==g share, STATIC unroll + predicated coef
    {
        #pragma unroll
        for (int v = 0; v < 4; v++){
            float c1 = (v == g) ? wu[v * 33 + 32]       : 0.f;
            float c2 = (v == g) ? wu[(4 + v) * 33 + 32] : 0.f;
            #pragma unroll
            for (int i = 0; i < 3; i++){
                #pragma unroll
                for (int j = 0; j < 3; j++){
                    const int e = i*3+j, eT = j*3+i;
                    cre[e] = fmaf(c1, wr[v][e],  cre[e]);
                    cre[e] = fmaf(c2, wr[v][eT], cre[e]);
                    cim[e] = fmaf(c1, wi[v][e],  cim[e]);
                    cim[e] = fmaf(-c2, wi[v][eT], cim[e]);
                }
            }
        }
        if (g == 0){
            float c8 = wu[8 * 33 + 32];
            cre[0] += c8; cre[4] += c8; cre[8] += c8;
        }
    }

    // --- main loop: 4 w16 slots for this thread
    const float* tbase = &lt[sl * TS_SITE];
    #pragma unroll
    for (int k = 0; k < 4; k++){
        const int w16 = g * 4 + k;
        float tre[9], tim[9];
        {
            const float2* tp = (const float2*)(tbase + w16 * TS_W);
            #pragma unroll
            for (int e = 0; e < 9; e++){ float2 d = tp[e]; tre[e] = d.x; tim[e] = d.y; }
        }
        float nre[9], nim[9];

        // N1 = sum_v weight[u,v,w16] * w_full[v];  C += N1 @ T
        {
            float cv[9];
            #pragma unroll
            for (int v = 0; v < 9; v++) cv[v] = wu[v * 33 + w16];
            #pragma unroll
            for (int i = 0; i < 3; i++){
                #pragma unroll
                for (int j = 0; j < 3; j++){
                    const int e = i*3+j, eT = j*3+i;
                    float nr = (i == j) ? cv[8] : 0.f;
                    float ni = 0.f;
                    #pragma unroll
                    for (int v = 0; v < 4; v++){
                        nr = fmaf(cv[v],    wr[v][e],  nr);
                        nr = fmaf(cv[4+v],  wr[v][eT], nr);
                        ni = fmaf(cv[v],    wi[v][e],  ni);
                        ni = fmaf(-cv[4+v], wi[v][eT], ni);
                    }
                    nre[e] = nr; nim[e] = ni;
                }
            }
        }
        #pragma unroll
        for (int i = 0; i < 3; i++){
            #pragma unroll
            for (int kk = 0; kk < 3; kk++){
                float ar = cre[i*3+kk], ai = cim[i*3+kk];
                #pragma unroll
                for (int j = 0; j < 3; j++){
                    float n_r = nre[i*3+j], n_i = nim[i*3+j];
                    float b_r = tre[j*3+kk], b_i = tim[j*3+kk];
                    ar = fmaf(n_r, b_r, ar); ar = fmaf(-n_i, b_i, ar);
                    ai = fmaf(n_r, b_i, ai); ai = fmaf(n_i, b_r, ai);
                }
                cre[i*3+kk] = ar; cim[i*3+kk] = ai;
            }
        }

        // N2 = sum_v weight[u,v,16+w16] * w_full[v];  C += N2 @ T^+
        {
            float cv[9];
            #pragma unroll
            for (int v = 0; v < 9; v++) cv[v] = wu[v * 33 + 16 + w16];
            #pragma unroll
            for (int i = 0; i < 3; i++){
                #pragma unroll
                for (int j = 0; j < 3; j++){
                    const int e = i*3+j, eT = j*3+i;
                    float nr = (i == j) ? cv[8] : 0.f;
                    float ni = 0.f;
                    #pragma unroll
                    for (int v = 0; v < 4; v++){
                        nr = fmaf(cv[v],    wr[v][e],  nr);
                        nr = fmaf(cv[4+v],  wr[v][eT], nr);
                        ni = fmaf(cv[v],    wi[v][e],  ni);
                        ni = fmaf(-cv[4+v], wi[v][eT], ni);
                    }
                    nre[e] = nr; nim[e] = ni;
                }
            }
        }
        #pragma unroll
        for (int i = 0; i < 3; i++){
            #pragma unroll
            for (int kk = 0; kk < 3; kk++){
                float ar = cre[i*3+kk], ai = cim[i*3+kk];
                #pragma unroll
                for (int j = 0; j < 3; j++){
                    float n_r = nre[i*3+j], n_i = nim[i*3+j];
                    // T^+[j,kk] = ( tre[kk*3+j], -tim[kk*3+j] )
                    float b_r = tre[kk*3+j], b_i = tim[kk*3+j];
                    ar = fmaf(n_r, b_r, ar); ar = fmaf(n_i, b_i, ar);
                    ai = fmaf(-n_r, b_i, ai); ai = fmaf(n_i, b_r, ai);
                }
                cre[i*3+kk] = ar; cim[i*3+kk] = ai;
            }
        }
    }

    // --- reduce partials over g (lane bits 0-1) and store
    #pragma unroll
    for (int e = 0; e < 9; e++){
        cre[e] += __shfl_xor(cre[e], 1);
        cre[e] += __shfl_xor(cre[e], 2);
        cim[e] += __shfl_xor(cim[e], 1);
        cim[e] += __shfl_xor(cim[e], 2);
    }
    if (g == 0){
        float2* dst = o2 + (s * 8 + 4 + u) * 9;
        #pragma unroll
        for (int e = 0; e < 9; e++){ float2 d; d.x = cre[e]; d.y = cim[e]; dst[e] = d; }
    }
}

extern "C" void kernel_launch(void* const* d_in, const int* in_sizes, int n_in,
                              void* d_out, int out_size, void* d_ws, size_t ws_size,
                              hipStream_t stream)
{
    const float* x = (const float*)d_in[0];
    const float* w = (const float*)d_in[1];
    float* out = (float*)d_out;
    dim3 grid(NSITES / SPB);
    dim3 block(TPB);
    hipLaunchKernelGGL(gcm_fused, grid, block, 0, stream, x, w, out);
}

// Round 7
// 88.424 us; speedup vs baseline: 2.2477x; 1.1164x over previous
//
#include <hip/hip_runtime.h>
#include <stdint.h>

// GCMConv on MI355X. Data model (verified rounds 0-3):
//   x      : float32 (1,16384,8,3,3,2)  — complex pair = float2
//   weight : float32 (4,9,33)
//   out    : float32 (1,16384,8,3,3,2)
//
// out[u] = sum_{w16<16} ( N1 @ t[w16] + N2 @ t[w16]^+ ) + N(w=32)
//   Nk = sum_v weight[u,v,wk] * w_full[v],  w_full = [w0..3, w0..3^+, I].
//
// 16 threads per site (u=out-channel, g=w16-quarter); shfl_xor reduce over g.
// Round-7: (a) __launch_bounds__(256,1) — rounds 4-6 showed the allocator
// pinning VGPR to the 128 wave-slot cliff and spilling ~400 B/thread;
// (b) N built ROW-WISE and consumed immediately (peak live ~123 floats < 128)
// so the kernel can be spill-free even at the 128-reg budget.

#define SPB 16            // sites per block
#define TPB 256           // 16 threads per site
#define NSITES 16384
#define TS_SITE 292       // 16*18 floats + 4 pad
#define TS_W 18
#define NWGT 1188         // 4*9*33

__device__ __forceinline__ int neigh(int s, int a){
    // dims (8,8,16,16): d3 bits[0:4), d2 bits[4:8), d1 bits[8:11), d0 bits[11:14)
    if (a == 3) return (s & ~15)        | ((s + 1)    & 15);
    if (a == 2) return (s & ~(15 << 4)) | ((s + 16)   & (15 << 4));
    if (a == 1) return (s & ~(7 << 8))  | ((s + 256)  & (7 << 8));
    return              (s & ~(7 << 11))| ((s + 2048) & (7 << 11));
}

__global__ __launch_bounds__(TPB, 1)
void gcm_fused(const float* __restrict__ xp,
               const float* __restrict__ wgt,
               float* __restrict__ outp)
{
    __shared__ float lt[SPB * TS_SITE];
    __shared__ float wsm[NWGT];
    const float2* x2 = (const float2*)xp;
    float2* o2 = (float2*)outp;

    const int tid = threadIdx.x;
    const int g   = tid & 3;            // lane bits 0-1 -> shfl_xor reduction
    const int u   = (tid >> 2) & 3;     // output channel / phase1 axis
    const int sl  = tid >> 4;           // site within block
    const int s   = blockIdx.x * SPB + sl;

    // stage weights to LDS
    for (int idx = tid; idx < NWGT; idx += TPB) wsm[idx] = wgt[idx];

    // ============ phase 1: one transport per thread: t[a*4+i] = U_a W_i(s+a^) U_a^+
    {
        const int a = u, i = g;
        float ure[9], uim[9];
        const float2* up = x2 + (s * 8 + a) * 9;
        #pragma unroll
        for (int e = 0; e < 9; e++){ float2 d = up[e]; ure[e] = d.x; uim[e] = d.y; }
        const int sn = neigh(s, a);
        float wre[9], wim[9];
        const float2* wp = x2 + (sn * 8 + 4 + i) * 9;
        #pragma unroll
        for (int e = 0; e < 9; e++){ float2 d = wp[e]; wre[e] = d.x; wim[e] = d.y; }

        float t1re[9], t1im[9];
        #pragma unroll
        for (int r = 0; r < 3; r++){
            #pragma unroll
            for (int k = 0; k < 3; k++){
                float ar = 0.f, ai = 0.f;
                #pragma unroll
                for (int j = 0; j < 3; j++){
                    float a_r = ure[r*3+j], a_i = uim[r*3+j];
                    float b_r = wre[j*3+k], b_i = wim[j*3+k];
                    ar = fmaf(a_r, b_r, ar); ar = fmaf(-a_i, b_i, ar);
                    ai = fmaf(a_r, b_i, ai); ai = fmaf(a_i, b_r, ai);
                }
                t1re[r*3+k] = ar; t1im[r*3+k] = ai;
            }
        }
        // T = T1 * U^+
        float* dst = &lt[sl * TS_SITE + (a * 4 + i) * TS_W];
        #pragma unroll
        for (int r = 0; r < 3; r++){
            #pragma unroll
            for (int k = 0; k < 3; k++){
                float ar = 0.f, ai = 0.f;
                #pragma unroll
                for (int j = 0; j < 3; j++){
                    float a_r = t1re[r*3+j], a_i = t1im[r*3+j];
                    float b_r = ure[k*3+j], b_i = uim[k*3+j];
                    ar = fmaf(a_r, b_r, ar); ar = fmaf(a_i, b_i, ar);
                    ai = fmaf(a_i, b_r, ai); ai = fmaf(-a_r, b_i, ai);
                }
                dst[(r*3+k)*2]     = ar;
                dst[(r*3+k)*2 + 1] = ai;
            }
        }
    }
    __syncthreads();

    // ============ phase 2 ============
    // pass-through copy of u channels (one quarter of lanes)
    if (g == 1){
        const float2* src = x2 + (s * 8 + u) * 9;
        float2* dst = o2 + (s * 8 + u) * 9;
        #pragma unroll
        for (int e = 0; e < 9; e++) dst[e] = src[e];
    }

    // own-site w matrices -> registers (ALL indices compile-time static)
    float wr[4][9], wi[4][9];
    #pragma unroll
    for (int v = 0; v < 4; v++){
        const float2* wp = x2 + (s * 8 + 4 + v) * 9;
        #pragma unroll
        for (int e = 0; e < 9; e++){ float2 d = wp[e]; wr[v][e] = d.x; wi[v][e] = d.y; }
    }

    float cre[9], cim[9];
    #pragma unroll
    for (int e = 0; e < 9; e++){ cre[e] = 0.f; cim[e] = 0.f; }

    const float* wu = wsm + u * 297;     // weight[u][v][w], stride 33 per v

    // --- w == 32 identity term: thread's v==g share, STATIC unroll + predicated coef
    {
        #pragma unroll
        for (int v = 0; v < 4; v++){
            float c1 = (v == g) ? wu[v * 33 + 32]       : 0.f;
            float c2 = (v == g) ? wu[(4 + v) * 33 + 32] : 0.f;
            #pragma unroll
            for (int i = 0; i < 3; i++){
                #pragma unroll
                for (int j = 0; j < 3; j++){
                    const int e = i*3+j, eT = j*3+i;
                    cre[e] = fmaf(c1, wr[v][e],  cre[e]);
                    cre[e] = fmaf(c2, wr[v][eT], cre[e]);
                    cim[e] = fmaf(c1, wi[v][e],  cim[e]);
                    cim[e] = fmaf(-c2, wi[v][eT], cim[e]);
                }
            }
        }
        if (g == 0){
            float c8 = wu[8 * 33 + 32];
            cre[0] += c8; cre[4] += c8; cre[8] += c8;
        }
    }

    // --- main loop: 4 w16 slots for this thread; N built row-wise (low live set)
    const float* tbase = &lt[sl * TS_SITE];
    #pragma unroll
    for (int k = 0; k < 4; k++){
        const int w16 = g * 4 + k;
        float tre[9], tim[9];
        {
            const float2* tp = (const float2*)(tbase + w16 * TS_W);
            #pragma unroll
            for (int e = 0; e < 9; e++){ float2 d = tp[e]; tre[e] = d.x; tim[e] = d.y; }
        }

        // ---- pass 1: C += N1 @ T, N1 row i built then consumed immediately
        {
            float cv[9];
            #pragma unroll
            for (int v = 0; v < 9; v++) cv[v] = wu[v * 33 + w16];
            #pragma unroll
            for (int i = 0; i < 3; i++){
                float nrr[3], nri[3];
                #pragma unroll
                for (int j = 0; j < 3; j++){
                    const int e = i*3+j, eT = j*3+i;
                    float nr = (i == j) ? cv[8] : 0.f;
                    float ni = 0.f;
                    #pragma unroll
                    for (int v = 0; v < 4; v++){
                        nr = fmaf(cv[v],    wr[v][e],  nr);
                        nr = fmaf(cv[4+v],  wr[v][eT], nr);
                        ni = fmaf(cv[v],    wi[v][e],  ni);
                        ni = fmaf(-cv[4+v], wi[v][eT], ni);
                    }
                    nrr[j] = nr; nri[j] = ni;
                }
                #pragma unroll
                for (int kk = 0; kk < 3; kk++){
                    float ar = cre[i*3+kk], ai = cim[i*3+kk];
                    #pragma unroll
                    for (int j = 0; j < 3; j++){
                        float b_r = tre[j*3+kk], b_i = tim[j*3+kk];
                        ar = fmaf(nrr[j], b_r, ar); ar = fmaf(-nri[j], b_i, ar);
                        ai = fmaf(nrr[j], b_i, ai); ai = fmaf(nri[j], b_r, ai);
                    }
                    cre[i*3+kk] = ar; cim[i*3+kk] = ai;
                }
            }
        }

        // ---- pass 2: C += N2 @ T^+, row-wise
        {
            float cv[9];
            #pragma unroll
            for (int v = 0; v < 9; v++) cv[v] = wu[v * 33 + 16 + w16];
            #pragma unroll
            for (int i = 0; i < 3; i++){
                float nrr[3], nri[3];
                #pragma unroll
                for (int j = 0; j < 3; j++){
                    const int e = i*3+j, eT = j*3+i;
                    float nr = (i == j) ? cv[8] : 0.f;
                    float ni = 0.f;
                    #pragma unroll
                    for (int v = 0; v < 4; v++){
                        nr = fmaf(cv[v],    wr[v][e],  nr);
                        nr = fmaf(cv[4+v],  wr[v][eT], nr);
                        ni = fmaf(cv[v],    wi[v][e],  ni);
                        ni = fmaf(-cv[4+v], wi[v][eT], ni);
                    }
                    nrr[j] = nr; nri[j] = ni;
                }
                #pragma unroll
                for (int kk = 0; kk < 3; kk++){
                    float ar = cre[i*3+kk], ai = cim[i*3+kk];
                    #pragma unroll
                    for (int j = 0; j < 3; j++){
                        // T^+[j,kk] = ( tre[kk*3+j], -tim[kk*3+j] )
                        float b_r = tre[kk*3+j], b_i = tim[kk*3+j];
                        ar = fmaf(nrr[j], b_r, ar); ar = fmaf(nri[j], b_i, ar);
                        ai = fmaf(-nrr[j], b_i, ai); ai = fmaf(nri[j], b_r, ai);
                    }
                    cre[i*3+kk] = ar; cim[i*3+kk] = ai;
                }
            }
        }
    }

    // --- reduce partials over g (lane bits 0-1) and store
    #pragma unroll
    for (int e = 0; e < 9; e++){
        cre[e] += __shfl_xor(cre[e], 1);
        cre[e] += __shfl_xor(cre[e], 2);
        cim[e] += __shfl_xor(cim[e], 1);
        cim[e] += __shfl_xor(cim[e], 2);
    }
    if (g == 0){
        float2* dst = o2 + (s * 8 + 4 + u) * 9;
        #pragma unroll
        for (int e = 0; e < 9; e++){ float2 d; d.x = cre[e]; d.y = cim[e]; dst[e] = d; }
    }
}

extern "C" void kernel_launch(void* const* d_in, const int* in_sizes, int n_in,
                              void* d_out, int out_size, void* d_ws, size_t ws_size,
                              hipStream_t stream)
{
    const float* x = (const float*)d_in[0];
    const float* w = (const float*)d_in[1];
    float* out = (float*)d_out;
    dim3 grid(NSITES / SPB);
    dim3 block(TPB);
    hipLaunchKernelGGL(gcm_fused, grid, block, 0, stream, x, w, out);
}